// Round 1
// baseline (196.151 us; speedup 1.0000x reference)
//
#include <hip/hip_runtime.h>
#include <math.h>

#define NOTES 88
#define TSTEPS 4000
#define CHUNKS 32
#define CHUNK_LEN 125   // CHUNKS * CHUNK_LEN == TSTEPS
#define WARM 17         // warmup rows (1 seed + 16 contraction steps); err ~2*0.3^16
#define ALPHA 0.3f
#define EPSV 1e-8f

__device__ __forceinline__ float wave_max(float v) {
#pragma unroll
    for (int d = 32; d > 0; d >>= 1) v = fmaxf(v, __shfl_xor(v, d));
    return v;
}
__device__ __forceinline__ float wave_sum(float v) {
#pragma unroll
    for (int d = 32; d > 0; d >>= 1) v += __shfl_xor(v, d);
    return v;
}

// Kernel 1: cur_probs = softmax(frame_logits, axis=-1), one wave per 88-wide row.
// Results are staged INTO d_out (kernel 2 reads then overwrites its own rows only).
__global__ __launch_bounds__(256) void softmax_rows(const float* __restrict__ f,
                                                    float* __restrict__ out,
                                                    int nrows) {
    const int wid  = threadIdx.x >> 6;
    const int lane = threadIdx.x & 63;
    const int r = blockIdx.x * 4 + wid;
    if (r >= nrows) return;
    const float* row = f + (size_t)r * NOTES;
    float v0 = row[lane];
    float v1 = (lane < NOTES - 64) ? row[64 + lane] : -INFINITY;
    float m = wave_max(fmaxf(v0, v1));
    float e0 = __expf(v0 - m);
    float e1 = (lane < NOTES - 64) ? __expf(v1 - m) : 0.f;
    float s = wave_sum(e0 + e1);
    float inv = 1.0f / s;
    float* orow = out + (size_t)r * NOTES;
    orow[lane] = e0 * inv;
    if (lane < NOTES - 64) orow[64 + lane] = e1 * inv;
}

// Kernel 2: chunked scan. Block = (batch b, chunk c). 128 threads, note j = tid (<88).
// Transition-prob column j lives in 88 VGPRs; p broadcast via LDS double buffer.
__global__ __launch_bounds__(128) void scan_kernel(const float* __restrict__ f,
                                                   const float* __restrict__ T,
                                                   float* __restrict__ out) {
    const int tid = threadIdx.x;
    const int b = blockIdx.x / CHUNKS;
    const int c = blockIdx.x % CHUNKS;
    const int j = tid;
    const bool act = (j < NOTES);
    const int wid = tid >> 6, lane = tid & 63;

    __shared__ float pbuf[2][NOTES];
    __shared__ float redm[2], reds[2];
    __shared__ float rm[NOTES], rsi[NOTES];

    // --- row-softmax stats of transition_logits (thread j owns row j) ---
    if (act) {
        const float* trow = T + (size_t)j * NOTES;
        float m = -INFINITY;
#pragma unroll 8
        for (int k = 0; k < NOTES; ++k) m = fmaxf(m, trow[k]);
        float s = 0.f;
#pragma unroll 8
        for (int k = 0; k < NOTES; ++k) s += __expf(trow[k] - m);
        rm[j] = m;
        rsi[j] = 1.0f / s;
    }
    __syncthreads();

    // tc[k] = trans_probs[k][j]  (column j, in registers)
    float tc[NOTES];
    if (act) {
#pragma unroll
        for (int k = 0; k < NOTES; ++k)
            tc[k] = __expf(T[(size_t)k * NOTES + j] - rm[k]) * rsi[k];
    }

    const float inv_norm = 1.0f / (1.0f + (float)NOTES * EPSV);
    const float* fb = f + (size_t)b * TSTEPS * NOTES;
    float* ob = out + (size_t)b * TSTEPS * NOTES;
    const int t0 = c * CHUNK_LEN;

    int cur = 0;
    if (c == 0) {
        // exact start: p0 = softmax(f row 0) (precomputed in ob row 0);
        // output row 0 is the RAW logits row.
        if (act) pbuf[0][j] = ob[j];
        __syncthreads();
        if (act) ob[j] = fb[j];
    } else {
        // warmup: seed with softmax(f row s0), run WARM-1 contraction steps
        const int s0 = t0 - WARM;
        {
            float v = act ? fb[(size_t)s0 * NOTES + j] : -INFINITY;
            float wm = wave_max(v);
            if (lane == 0) redm[wid] = wm;
            __syncthreads();
            float m = fmaxf(redm[0], redm[1]);
            float e = act ? __expf(v - m) : 0.f;
            float ws = wave_sum(e);
            if (lane == 0) reds[wid] = ws;
            __syncthreads();
            float s = reds[0] + reds[1];
            if (act) pbuf[0][j] = e / s;
            __syncthreads();
        }
        for (int t = s0 + 1; t < t0; ++t) {
            float v = act ? fb[(size_t)t * NOTES + j] : -INFINITY;
            float wm = wave_max(v);
            if (lane == 0) redm[wid] = wm;
            __syncthreads();
            float m = fmaxf(redm[0], redm[1]);
            float e = act ? __expf(v - m) : 0.f;
            float ws = wave_sum(e);
            if (lane == 0) reds[wid] = ws;
            __syncthreads();
            float s = reds[0] + reds[1];
            float cp = e / s;

            float acc = 0.f;
            if (act) {
                const float4* p4 = (const float4*)pbuf[cur];
#pragma unroll
                for (int kk = 0; kk < NOTES / 4; ++kk) {
                    float4 pv = p4[kk];
                    acc += pv.x * tc[4 * kk + 0];
                    acc += pv.y * tc[4 * kk + 1];
                    acc += pv.z * tc[4 * kk + 2];
                    acc += pv.w * tc[4 * kk + 3];
                }
            }
            float blended = ALPHA * acc + (1.0f - ALPHA) * cp;
            float pn = (blended + EPSV) * inv_norm;
            if (act) pbuf[cur ^ 1][j] = pn;
            __syncthreads();
            cur ^= 1;
        }
    }

    // --- main loop: read precomputed cur-probs from ob row t, overwrite with output ---
    const int tend = t0 + CHUNK_LEN;
    const int tstart = (c == 0) ? 1 : t0;
    float nxt = 0.f;
    if (act) nxt = ob[(size_t)tstart * NOTES + j];
    for (int t = tstart; t < tend; ++t) {
        float cp = nxt;
        if (act && (t + 1 < tend)) nxt = ob[(size_t)(t + 1) * NOTES + j];  // prefetch

        float acc = 0.f;
        if (act) {
            const float4* p4 = (const float4*)pbuf[cur];
#pragma unroll
            for (int kk = 0; kk < NOTES / 4; ++kk) {
                float4 pv = p4[kk];
                acc += pv.x * tc[4 * kk + 0];
                acc += pv.y * tc[4 * kk + 1];
                acc += pv.z * tc[4 * kk + 2];
                acc += pv.w * tc[4 * kk + 3];
            }
        }
        float blended = ALPHA * acc + (1.0f - ALPHA) * cp;
        float pn = (blended + EPSV) * inv_norm;
        if (act) {
            ob[(size_t)t * NOTES + j] = __logf(blended + EPSV);
            pbuf[cur ^ 1][j] = pn;
        }
        __syncthreads();
        cur ^= 1;
    }
}

extern "C" void kernel_launch(void* const* d_in, const int* in_sizes, int n_in,
                              void* d_out, int out_size, void* d_ws, size_t ws_size,
                              hipStream_t stream) {
    const float* f = (const float*)d_in[0];
    const float* T = (const float*)d_in[1];
    float* out = (float*)d_out;

    const int batch = in_sizes[0] / (TSTEPS * NOTES);
    const int nrows = batch * TSTEPS;

    softmax_rows<<<(nrows + 3) / 4, 256, 0, stream>>>(f, out, nrows);
    scan_kernel<<<batch * CHUNKS, 128, 0, stream>>>(f, T, out);
}

// Round 2
// 133.001 us; speedup vs baseline: 1.4748x; 1.4748x over previous
//
#include <hip/hip_runtime.h>
#include <math.h>

#define NOTES 88
#define TSTEPS 4000
#define NCHUNK 64
#define WARM 12
#define EPSV 1e-8f
#define PSTR 104  // ushort stride per chain (208B, breaks bank alignment)

typedef __attribute__((ext_vector_type(8))) short short8;
typedef __attribute__((ext_vector_type(4))) float f32x4;

__device__ __forceinline__ unsigned cvt_pk_bf16(float lo, float hi) {
    unsigned r;
    asm("v_cvt_pk_bf16_f32 %0, %1, %2" : "=v"(r) : "v"(lo), "v"(hi));
    return r;
}

// One wave (64 threads) per block. Block = (b-group of 16 chains, chunk c).
// lane l: chain m = l&15, quad-group hi = l>>4.
// MFMA: D[n][m] = sum_k Tp[k][n] * p_m[k]  via A' = Tp^T (frags in VGPRs),
// B' = p (from LDS, bf16). D layout: chain = lane&15, note n = 16*nt + 4*hi + reg
// == same layout as the in-register row softmax. No __syncthreads anywhere.
__global__ __launch_bounds__(64, 1)
void fused_scan(const float* __restrict__ f, const float* __restrict__ T,
                float* __restrict__ out) {
    const int l = threadIdx.x;
    const int m = l & 15, hi = l >> 4;
    const int c = blockIdx.x & (NCHUNK - 1);
    const int bg = blockIdx.x >> 6;
    const int b = bg * 16 + m;

    __shared__ float sM[96], sI[96];
    __shared__ unsigned short pls[16 * PSTR];

    // ---- transition-row softmax stats (rows round-robin over lanes) ----
    for (int r = l; r < NOTES; r += 64) {
        const float4* row = (const float4*)(T + r * NOTES);
        float4 v[22];
#pragma unroll
        for (int q = 0; q < 22; ++q) v[q] = row[q];
        float mx = -1e30f;
#pragma unroll
        for (int q = 0; q < 22; ++q)
            mx = fmaxf(mx, fmaxf(fmaxf(v[q].x, v[q].y), fmaxf(v[q].z, v[q].w)));
        float s = 0.f;
#pragma unroll
        for (int q = 0; q < 22; ++q)
            s += __expf(v[q].x - mx) + __expf(v[q].y - mx) +
                 __expf(v[q].z - mx) + __expf(v[q].w - mx);
        sM[r] = mx;
        sI[r] = 1.0f / s;
    }
    __syncthreads();

    // ---- loop-invariant A' fragments: Af[nt][kt], A'[n][k] = transP[k][n] ----
    // A-frag layout (16x16x32): lane holds row = l&15, k = 32*kt + 8*hi + e.
    short8 Af[6][3];
#pragma unroll
    for (int nt = 0; nt < 6; ++nt) {
        const int n = nt * 16 + m;
#pragma unroll
        for (int kt = 0; kt < 3; ++kt) {
            float v[8];
#pragma unroll
            for (int e = 0; e < 8; ++e) {
                const int k = kt * 32 + hi * 8 + e;
                float val = 0.f;
                if (k < NOTES && n < NOTES)
                    val = __expf(T[k * NOTES + n] - sM[k]) * sI[k];
                v[e] = val;
            }
            union { unsigned u[4]; short8 s8; } uu;
#pragma unroll
            for (int q = 0; q < 4; ++q) uu.u[q] = cvt_pk_bf16(v[2 * q], v[2 * q + 1]);
            Af[nt][kt] = uu.s8;
        }
    }

    // ---- chunk geometry: 4000 = 32*63 + 32*62 ----
    const int LEN = 62 + (c < 32 ? 1 : 0);
    const int t0 = 62 * c + (c < 32 ? c : 32);
    const int tend = t0 + LEN;
    const int tfirst = (c == 0) ? 0 : t0 - WARM;
    const int tstore = (c == 0) ? 1 : t0;
    const float inv_norm = 1.0f / (1.0f + (float)NOTES * EPSV);

    const float* fb = f + (size_t)b * TSTEPS * NOTES;
    float* ob = out + (size_t)b * TSTEPS * NOTES;
    const bool padq = (80 + 4 * hi) >= NOTES;  // this lane's nt=5 quad is padding
    unsigned short* pbase = pls + m * PSTR;

    auto loadRow = [&](int t, float4 (&rv)[6]) {
        const float4* rp = (const float4*)(fb + (size_t)t * NOTES);
#pragma unroll
        for (int nt = 0; nt < 6; ++nt) {
            int idx = 4 * nt + hi;
            if (nt == 5 && padq) idx = 0;  // clamp pad address in-bounds
            rv[nt] = rp[idx];
        }
        if (padq) { rv[5].x = -1e30f; rv[5].y = -1e30f; rv[5].z = -1e30f; rv[5].w = -1e30f; }
    };

    auto softmaxRow = [&](const float4 (&rv)[6], float4 (&cp)[6]) {
        float mx = -1e30f;
#pragma unroll
        for (int nt = 0; nt < 6; ++nt)
            mx = fmaxf(mx, fmaxf(fmaxf(rv[nt].x, rv[nt].y), fmaxf(rv[nt].z, rv[nt].w)));
        mx = fmaxf(mx, __shfl_xor(mx, 16));
        mx = fmaxf(mx, __shfl_xor(mx, 32));
        float s = 0.f;
#pragma unroll
        for (int nt = 0; nt < 6; ++nt) {
            cp[nt].x = __expf(rv[nt].x - mx);
            cp[nt].y = __expf(rv[nt].y - mx);
            cp[nt].z = __expf(rv[nt].z - mx);
            cp[nt].w = __expf(rv[nt].w - mx);
            s += cp[nt].x + cp[nt].y + cp[nt].z + cp[nt].w;
        }
        s += __shfl_xor(s, 16);
        s += __shfl_xor(s, 32);
        const float inv = 1.0f / s;
#pragma unroll
        for (int nt = 0; nt < 6; ++nt) {
            cp[nt].x *= inv; cp[nt].y *= inv; cp[nt].z *= inv; cp[nt].w *= inv;
        }
    };

    auto writeP = [&](const float4 (&p)[6]) {
#pragma unroll
        for (int nt = 0; nt < 6; ++nt) {
            float4 v = p[nt];
            if (nt == 5 && padq) { v.x = 0.f; v.y = 0.f; v.z = 0.f; v.w = 0.f; }
            uint2 w;
            w.x = cvt_pk_bf16(v.x, v.y);
            w.y = cvt_pk_bf16(v.z, v.w);
            *(uint2*)(pbase + 16 * nt + 4 * hi) = w;  // notes n..n+3, bf16
        }
    };

    auto step = [&](const float4 (&cur)[6], int t) {
        float4 cp[6];
        softmaxRow(cur, cp);
        // B' frags: lane holds col = m, k = 32*kt + 8*hi + e (16B contiguous)
        short8 Bf[3];
#pragma unroll
        for (int kt = 0; kt < 3; ++kt)
            Bf[kt] = *(const short8*)(pbase + 32 * kt + 8 * hi);
        f32x4 acc[6];
#pragma unroll
        for (int nt = 0; nt < 6; ++nt) acc[nt] = (f32x4){0.f, 0.f, 0.f, 0.f};
#pragma unroll
        for (int kt = 0; kt < 3; ++kt) {
#pragma unroll
            for (int nt = 0; nt < 6; ++nt)
                acc[nt] = __builtin_amdgcn_mfma_f32_16x16x32_bf16(
                    Af[nt][kt], Bf[kt], acc[nt], 0, 0, 0);
        }
        const bool st = (t >= tstore);
        float4 pn[6];
#pragma unroll
        for (int nt = 0; nt < 6; ++nt) {
            float4 x;
            x.x = fmaf(0.3f, acc[nt][0], fmaf(0.7f, cp[nt].x, EPSV));
            x.y = fmaf(0.3f, acc[nt][1], fmaf(0.7f, cp[nt].y, EPSV));
            x.z = fmaf(0.3f, acc[nt][2], fmaf(0.7f, cp[nt].z, EPSV));
            x.w = fmaf(0.3f, acc[nt][3], fmaf(0.7f, cp[nt].w, EPSV));
            pn[nt].x = x.x * inv_norm;
            pn[nt].y = x.y * inv_norm;
            pn[nt].z = x.z * inv_norm;
            pn[nt].w = x.w * inv_norm;
            if (st && !(nt == 5 && padq)) {
                float4 o;
                o.x = __logf(x.x);
                o.y = __logf(x.y);
                o.z = __logf(x.z);
                o.w = __logf(x.w);
                *(float4*)(ob + (size_t)t * NOTES + 16 * nt + 4 * hi) = o;
            }
        }
        writeP(pn);
    };

    // ---- seed ----
    float4 rA[6], rB[6];
    loadRow(tfirst, rA);
    {
        float4 cp[6];
        softmaxRow(rA, cp);
        if (c == 0) {
            // output row 0 is the RAW logits row
#pragma unroll
            for (int nt = 0; nt < 6; ++nt)
                if (!(nt == 5 && padq))
                    *(float4*)(ob + 16 * nt + 4 * hi) = rA[nt];
        }
        writeP(cp);
    }

    // ---- main loop, double-buffered register prefetch ----
    int t = tfirst + 1;
    loadRow(t, rB);
    while (true) {
        {
            const int tn = (t + 1 < tend) ? t + 1 : t;
            loadRow(tn, rA);  // prefetch next while stepping on rB
        }
        step(rB, t);
        if (++t >= tend) break;
        {
            const int tn = (t + 1 < tend) ? t + 1 : t;
            loadRow(tn, rB);
        }
        step(rA, t);
        if (++t >= tend) break;
    }
}

extern "C" void kernel_launch(void* const* d_in, const int* in_sizes, int n_in,
                              void* d_out, int out_size, void* d_ws, size_t ws_size,
                              hipStream_t stream) {
    const float* f = (const float*)d_in[0];
    const float* T = (const float*)d_in[1];
    float* out = (float*)d_out;
    const int batch = in_sizes[0] / (TSTEPS * NOTES);  // 64
    const int blocks = (batch / 16) * NCHUNK;          // 256
    fused_scan<<<blocks, 64, 0, stream>>>(f, T, out);
}

// Round 3
// 63.709 us; speedup vs baseline: 3.0788x; 2.0876x over previous
//
#include <hip/hip_runtime.h>
#include <math.h>

#define NOTES 88
#define TSTEPS 4000
#define NCHUNK 256
#define WARM 12
#define EPSV 1e-8f
#define PSTR 100  // ushort stride per chain: 200B, /4=50 => 16 chains hit 16 distinct banks

typedef __attribute__((ext_vector_type(8))) short short8;
typedef __attribute__((ext_vector_type(4))) float f32x4;

__device__ __forceinline__ unsigned cvt_pk_bf16(float lo, float hi) {
    unsigned r;
    asm("v_cvt_pk_bf16_f32 %0, %1, %2" : "=v"(r) : "v"(lo), "v"(hi));
    return r;
}

// One wave (64 threads) per block. Block = (b-group of 16 chains, chunk c).
// lane l: chain m = l&15, quad-group hi = l>>4.
// MFMA: D[n][m] = sum_k Tp[k][n] * p_m[k]  via A' = Tp^T (frags in VGPRs),
// B' = p (from LDS, bf16). D layout (chain = lane&15, note = 16*nt + 4*hi + reg)
// matches the in-register row-softmax layout. No barriers in the loop.
__global__ __launch_bounds__(64, 1)
void fused_scan(const float* __restrict__ f, const float* __restrict__ T,
                float* __restrict__ out) {
    const int l = threadIdx.x;
    const int m = l & 15, hi = l >> 4;
    const int c = blockIdx.x & (NCHUNK - 1);
    const int bg = blockIdx.x >> 8;  // NCHUNK=256
    const int b = bg * 16 + m;

    __shared__ float sM[96], sI[96];
    __shared__ unsigned short pls[16 * PSTR];

    // ---- transition-row softmax stats (rows round-robin over lanes) ----
    for (int r = l; r < NOTES; r += 64) {
        const float4* row = (const float4*)(T + r * NOTES);
        float4 v[22];
#pragma unroll
        for (int q = 0; q < 22; ++q) v[q] = row[q];
        float mx = -1e30f;
#pragma unroll
        for (int q = 0; q < 22; ++q)
            mx = fmaxf(mx, fmaxf(fmaxf(v[q].x, v[q].y), fmaxf(v[q].z, v[q].w)));
        float s = 0.f;
#pragma unroll
        for (int q = 0; q < 22; ++q)
            s += __expf(v[q].x - mx) + __expf(v[q].y - mx) +
                 __expf(v[q].z - mx) + __expf(v[q].w - mx);
        sM[r] = mx;
        sI[r] = 1.0f / s;
    }
    __syncthreads();

    // ---- loop-invariant A' fragments: Af[nt][kt], A'[n][k] = transP[k][n] ----
    // A-frag layout (16x16x32): lane holds row = l&15, k = 32*kt + 8*hi + e.
    short8 Af[6][3];
#pragma unroll
    for (int nt = 0; nt < 6; ++nt) {
        const int n = nt * 16 + m;
#pragma unroll
        for (int kt = 0; kt < 3; ++kt) {
            float v[8];
#pragma unroll
            for (int e = 0; e < 8; ++e) {
                const int k = kt * 32 + hi * 8 + e;
                float val = 0.f;
                if (k < NOTES && n < NOTES)
                    val = __expf(T[k * NOTES + n] - sM[k]) * sI[k];
                v[e] = val;
            }
            union { unsigned u[4]; short8 s8; } uu;
#pragma unroll
            for (int q = 0; q < 4; ++q) uu.u[q] = cvt_pk_bf16(v[2 * q], v[2 * q + 1]);
            Af[nt][kt] = uu.s8;
        }
    }

    // ---- chunk geometry: 4000 = 160*16 + 96*15 ----
    const int LEN = (c < 160) ? 16 : 15;
    const int t0 = (c < 160) ? 16 * c : 15 * c + 160;
    const int tend = t0 + LEN;
    const int tfirst = (c == 0) ? 0 : t0 - WARM;
    const int tstore = (c == 0) ? 1 : t0;

    const float* fb = f + (size_t)b * TSTEPS * NOTES;
    float* ob = out + (size_t)b * TSTEPS * NOTES;
    const bool padq = (80 + 4 * hi) >= NOTES;  // this lane's nt=5 quad is padding
    unsigned short* pbase = pls + m * PSTR;

    auto loadRow = [&](int t, float4 (&rv)[6]) {
        const float4* rp = (const float4*)(fb + (size_t)t * NOTES);
#pragma unroll
        for (int nt = 0; nt < 6; ++nt) {
            int idx = 4 * nt + hi;
            if (nt == 5 && padq) idx = 0;  // clamp pad address in-bounds
            rv[nt] = rp[idx];
        }
        if (padq) { rv[5].x = -1e30f; rv[5].y = -1e30f; rv[5].z = -1e30f; rv[5].w = -1e30f; }
    };

    auto softmaxRow = [&](const float4 (&rv)[6], float4 (&cp)[6]) {
        float mx = -1e30f;
#pragma unroll
        for (int nt = 0; nt < 6; ++nt)
            mx = fmaxf(mx, fmaxf(fmaxf(rv[nt].x, rv[nt].y), fmaxf(rv[nt].z, rv[nt].w)));
        mx = fmaxf(mx, __shfl_xor(mx, 16));
        mx = fmaxf(mx, __shfl_xor(mx, 32));
        float s = 0.f;
#pragma unroll
        for (int nt = 0; nt < 6; ++nt) {
            cp[nt].x = __expf(rv[nt].x - mx);
            cp[nt].y = __expf(rv[nt].y - mx);
            cp[nt].z = __expf(rv[nt].z - mx);
            cp[nt].w = __expf(rv[nt].w - mx);
            s += cp[nt].x + cp[nt].y + cp[nt].z + cp[nt].w;
        }
        s += __shfl_xor(s, 16);
        s += __shfl_xor(s, 32);
        const float inv = 1.0f / s;
#pragma unroll
        for (int nt = 0; nt < 6; ++nt) {
            cp[nt].x *= inv; cp[nt].y *= inv; cp[nt].z *= inv; cp[nt].w *= inv;
        }
    };

    auto writeP = [&](const float4 (&p)[6]) {
        // pad lanes may write garbage for n>=88: the matching Af k-columns are 0.
#pragma unroll
        for (int nt = 0; nt < 6; ++nt) {
            uint2 w;
            w.x = cvt_pk_bf16(p[nt].x, p[nt].y);
            w.y = cvt_pk_bf16(p[nt].z, p[nt].w);
            *(uint2*)(pbase + 16 * nt + 4 * hi) = w;  // notes n..n+3, bf16
        }
    };

    auto readB = [&](short8 (&Bf)[3]) {
#pragma unroll
        for (int kt = 0; kt < 3; ++kt)
            Bf[kt] = *(const short8*)(pbase + 32 * kt + 8 * hi);
    };

    short8 Bf[3];

    auto step = [&](const float4 (&cur)[6], int t) {
        float4 cp[6];
        softmaxRow(cur, cp);
        f32x4 acc[6];
#pragma unroll
        for (int nt = 0; nt < 6; ++nt) acc[nt] = (f32x4){0.f, 0.f, 0.f, 0.f};
#pragma unroll
        for (int kt = 0; kt < 3; ++kt) {
#pragma unroll
            for (int nt = 0; nt < 6; ++nt)
                acc[nt] = __builtin_amdgcn_mfma_f32_16x16x32_bf16(
                    Af[nt][kt], Bf[kt], acc[nt], 0, 0, 0);
        }
        float4 x[6];
#pragma unroll
        for (int nt = 0; nt < 6; ++nt) {
            x[nt].x = fmaf(0.3f, acc[nt][0], fmaf(0.7f, cp[nt].x, EPSV));
            x[nt].y = fmaf(0.3f, acc[nt][1], fmaf(0.7f, cp[nt].y, EPSV));
            x[nt].z = fmaf(0.3f, acc[nt][2], fmaf(0.7f, cp[nt].z, EPSV));
            x[nt].w = fmaf(0.3f, acc[nt][3], fmaf(0.7f, cp[nt].w, EPSV));
        }
        writeP(x);          // critical path: feeds next step's B
        readB(Bf);          // issue next-step B read ASAP; log/store tail covers it
        if (t >= tstore) {
#pragma unroll
            for (int nt = 0; nt < 6; ++nt) {
                if (nt == 5 && padq) continue;
                float4 o;
                o.x = __logf(x[nt].x);
                o.y = __logf(x[nt].y);
                o.z = __logf(x[nt].z);
                o.w = __logf(x[nt].w);
                *(float4*)(ob + (size_t)t * NOTES + 16 * nt + 4 * hi) = o;
            }
        }
    };

    // ---- seed ----
    {
        float4 r0[6];
        loadRow(tfirst, r0);
        float4 cp[6];
        softmaxRow(r0, cp);
        if (c == 0) {
            // output row 0 is the RAW logits row
#pragma unroll
            for (int nt = 0; nt < 6; ++nt)
                if (!(nt == 5 && padq))
                    *(float4*)(ob + 16 * nt + 4 * hi) = r0[nt];
        }
        writeP(cp);
        readB(Bf);
    }

    // ---- main loop, 3 buffers / 2-deep prefetch (static indices only) ----
    float4 rA[6], rB[6], rC[6];
    int t = tfirst + 1;
    loadRow(t, rA);
    {
        const int tn = (t + 1 < tend) ? t + 1 : tend - 1;
        loadRow(tn, rB);
    }
    while (true) {
        {
            const int tn = (t + 2 < tend) ? t + 2 : tend - 1;
            loadRow(tn, rC);
        }
        step(rA, t);
        if (++t >= tend) break;
        {
            const int tn = (t + 2 < tend) ? t + 2 : tend - 1;
            loadRow(tn, rA);
        }
        step(rB, t);
        if (++t >= tend) break;
        {
            const int tn = (t + 2 < tend) ? t + 2 : tend - 1;
            loadRow(tn, rB);
        }
        step(rC, t);
        if (++t >= tend) break;
    }
}

extern "C" void kernel_launch(void* const* d_in, const int* in_sizes, int n_in,
                              void* d_out, int out_size, void* d_ws, size_t ws_size,
                              hipStream_t stream) {
    const float* f = (const float*)d_in[0];
    const float* T = (const float*)d_in[1];
    float* out = (float*)d_out;
    const int batch = in_sizes[0] / (TSTEPS * NOTES);  // 64
    const int blocks = (batch / 16) * NCHUNK;          // 1024
    fused_scan<<<blocks, 64, 0, stream>>>(f, T, out);
}